// Round 6
// baseline (540.723 us; speedup 1.0000x reference)
//
#include <hip/hip_runtime.h>

#define H 80
#define W 80
#define DD 20
#define C 32
#define NPOS (H*W)          // 6400
#define NP3 (NPOS*DD)       // 128000
#define SO 9
#define DO_ 5
#define NDISP (DO_*SO*SO)   // 405

#define NC 4                // channels staged per chunk
#define NCHUNK (C/NC)       // 8
#define XQ 20               // x-positions per block
#define COLS 28             // XQ + 8 halo columns (x2 = x-4 .. x+4+19)
#define ZST 28              // z stride: 2 front pad + 20 real + 6 back/bank pad
#define F2S_FLOATS (NC*COLS*ZST)   // 3136 floats = 12.25 KB
#define F1_SLOTS (NC*XQ*5)         // 400 float4 slots = 6.4 KB

typedef float nt4 __attribute__((ext_vector_type(4)));   // native vec for NT stores

// r5 (502-us) kernel + ONE change: f1 fragments are staged into LDS once per
// chunk (behind the SAME barrier as f2 staging) instead of being globally
// loaded 3x by the djg triplication. Cuts f1 global traffic 442->147 MB and
// removes global-load latency from the compute phase. Everything else
// (single-buffered f2 staging, 2 barriers/chunk, NT stores, XCD swizzle)
// untouched. FMA order bit-identical (absmax 0).
__global__ __launch_bounds__(320)
void fused_kernel(const float* __restrict__ f1, const float* __restrict__ a1,
                  const float* __restrict__ f2, const float* __restrict__ a2,
                  float* __restrict__ outc, float* __restrict__ outm)
{
    __shared__ __align__(16) float f2s[F2S_FLOATS];
    __shared__ __align__(16) float f1s[F1_SLOTS * 4];   // [c][xl][zq] float4 slots
    __shared__ float m1s[XQ];
    __shared__ float m2s[COLS];

    // XCD-aware swizzle: 2880 blocks % 8 == 0 -> 360 contiguous per XCD.
    // Consecutive-per-XCD blocks share y (36 blocks/y) -> f1/f2 rows stay L2-local.
    int bid = blockIdx.x;
    int swz = (bid & 7) * 360 + (bid >> 3);
    int y  = swz / 36;
    int r0 = swz % 36;
    int di = r0 >> 2;       // 0..8
    int xq = r0 & 3;        // 0..3

    int t   = threadIdx.x;
    int djg = t / 100;      // 0..2 (for active threads)
    int r   = t % 100;
    int xl  = r / 5;        // 0..19
    int zg  = r % 5;        // 0..4
    int z0  = zg * 4;
    int x   = xq * XQ + xl;
    int pos = y * W + x;
    int y2  = y + di - 4;
    bool y2ok = ((unsigned)y2 < (unsigned)H);
    bool act  = (t < 300);

    // f1 staging decomposition (slot s -> source): c=s/100, rem=s%100,
    // xls=rem/5, zqs=rem%5. Thread t stages slot t; threads 0..79 also t+320.
    int s0c = t / 100, s0r = t % 100;
    const float* f1row = f1 + (y * W + xq * XQ) * DD;   // + c*NP3 + xl*DD + zq*4

    // One-time zero of the f2 staging buffer: covers depth pads (zs 0,1 and
    // 22..27), OOR halo columns, and fully-OOR rows (y2ok == false).
    for (int i = t; i < F2S_FLOATS / 4; i += 320)
        ((float4*)f2s)[i] = make_float4(0.f, 0.f, 0.f, 0.f);

    // visibility row-sums (exact same arithmetic order as before)
    if (t < XQ){
        const float* p = a1 + (y * W + xq * XQ + t) * DD;
        float sm = 0.f;
        #pragma unroll
        for (int q = 0; q < 5; ++q){
            float4 v = *(const float4*)(p + q * 4);
            sm += v.x + v.y + v.z + v.w;
        }
        m1s[t] = fminf(fmaxf(sm, 0.f), 1.f);
    } else if (t >= 32 && t < 32 + COLS){
        int col = t - 32;
        int x2 = xq * XQ + col - 4;
        float m = 1.f;                       // spatial/row pad of mask2 is 1.0
        if (y2ok && ((unsigned)x2 < (unsigned)W)){
            const float* p = a2 + (y2 * W + x2) * DD;
            float sm = 0.f;
            #pragma unroll
            for (int q = 0; q < 5; ++q){
                float4 v = *(const float4*)(p + q * 4);
                sm += v.x + v.y + v.z + v.w;
            }
            m = fminf(fmaxf(sm, 0.f), 1.f);
        }
        m2s[col] = m;
    }
    __syncthreads();

    float acc[3][DO_][4];
    #pragma unroll
    for (int i = 0; i < 3; ++i)
        #pragma unroll
        for (int j = 0; j < DO_; ++j)
            #pragma unroll
            for (int k = 0; k < 4; ++k) acc[i][j][k] = 0.f;

    #pragma unroll 1
    for (int cc = 0; cc < NCHUNK; ++cc){
        // ---- stage NC channels of f2 row y2 into LDS (zs = z + 2) ----
        if (y2ok && t < NC * COLS){
            int c   = t / COLS;
            int col = t % COLS;
            int x2  = xq * XQ + col - 4;
            if ((unsigned)x2 < (unsigned)W){
                const float* p = f2 + (size_t)(cc * NC + c) * NP3 + (y2 * W + x2) * DD;
                float* d = f2s + (c * COLS + col) * ZST + 2;   // +2: front depth pad
                #pragma unroll
                for (int q = 0; q < 5; ++q){
                    float4 v = *(const float4*)(p + q * 4);
                    *(float2*)(d + q * 4)     = make_float2(v.x, v.y);
                    *(float2*)(d + q * 4 + 2) = make_float2(v.z, v.w);
                }
            }
        }
        // ---- stage f1 chunk tile into LDS: 400 float4 slots, coalesced ----
        {
            float4 v = *(const float4*)(f1row + (size_t)(cc * NC + s0c) * NP3
                                        + (s0r / 5) * DD + (s0r % 5) * 4);
            *(float4*)(f1s + t * 4) = v;
        }
        if (t < F1_SLOTS - 320){            // slots 320..399 (c=3, rem 20..99)
            int s  = t + 320;
            int rm = s % 100;
            float4 v = *(const float4*)(f1row + (size_t)(cc * NC + 3) * NP3
                                        + (rm / 5) * DD + (rm % 5) * 4);
            *(float4*)(f1s + s * 4) = v;
        }
        __syncthreads();
        if (act){
            #pragma unroll
            for (int c = 0; c < NC; ++c){
                float4 avv = *(const float4*)(f1s + (c * 100 + xl * 5 + zg) * 4);
                float av[4] = {avv.x, avv.y, avv.z, avv.w};
                #pragma unroll
                for (int djl = 0; djl < 3; ++djl){
                    int dj = djg * 3 + djl;
                    // window zs = z0 .. z0+7  <=>  zp = z0-2 .. z0+5 (16B aligned)
                    const float* bp = f2s + (c * COLS + xl + dj) * ZST + z0;
                    float4 b0 = *(const float4*)(bp);
                    float4 b1 = *(const float4*)(bp + 4);
                    float bb[8] = {b0.x, b0.y, b0.z, b0.w, b1.x, b1.y, b1.z, b1.w};
                    #pragma unroll
                    for (int dk = 0; dk < DO_; ++dk)
                        #pragma unroll
                        for (int z = 0; z < 4; ++z)
                            acc[djl][dk][z] = fmaf(av[z], bb[z + dk], acc[djl][dk][z]);
                }
            }
        }
        __syncthreads();
    }

    if (act){
        const float sc = 1.0f / 32.0f;
        float m1v = m1s[xl];
        #pragma unroll
        for (int djl = 0; djl < 3; ++djl){
            int dj = djg * 3 + djl;
            float m2v = m2s[xl + dj];            // 1.0 when spatially OOR -> mi == m1v
            float mi = fminf(m1v * m2v, 1.f);
            #pragma unroll
            for (int dk = 0; dk < DO_; ++dk){
                size_t off = (size_t)(dk * 81 + di * 9 + dj) * NP3 + pos * DD + z0;
                nt4 wv;
                wv.x = acc[djl][dk][0] * sc;
                wv.y = acc[djl][dk][1] * sc;
                wv.z = acc[djl][dk][2] * sc;
                wv.w = acc[djl][dk][3] * sc;
                __builtin_nontemporal_store(wv, (nt4*)(outc + off));
                int zlo = 2 - dk, zhi = 22 - dk;  // depth pad of mask2 = 1 -> m1v
                nt4 mv;
                mv.x = (z0 + 0 >= zlo && z0 + 0 < zhi) ? mi : m1v;
                mv.y = (z0 + 1 >= zlo && z0 + 1 < zhi) ? mi : m1v;
                mv.z = (z0 + 2 >= zlo && z0 + 2 < zhi) ? mi : m1v;
                mv.w = (z0 + 3 >= zlo && z0 + 3 < zhi) ? mi : m1v;
                __builtin_nontemporal_store(mv, (nt4*)(outm + off));
            }
        }
    }
}

extern "C" void kernel_launch(void* const* d_in, const int* in_sizes, int n_in,
                              void* d_out, int out_size, void* d_ws, size_t ws_size,
                              hipStream_t stream)
{
    const float* f1 = (const float*)d_in[0];   // mpi1_features [32][80][80][20] f32
    const float* a1 = (const float*)d_in[1];   // mpi1_alpha
    const float* f2 = (const float*)d_in[2];   // mpi2_features
    const float* a2 = (const float*)d_in[3];   // mpi2_alpha
    float* outc = (float*)d_out;                   // cost volume [405][6400][20]
    float* outm = outc + (size_t)NDISP * NP3;      // mask volume, same shape
    (void)d_ws; (void)ws_size; (void)in_sizes; (void)n_in;

    fused_kernel<<<80 * SO * 4, 320, 0, stream>>>(f1, a1, f2, a2, outc, outm);
}